// Round 6
// baseline (116.479 us; speedup 1.0000x reference)
//
#include <hip/hip_runtime.h>
#include <hip/hip_bf16.h>
#include <math.h>

// Problem constants
#define C_IN   256
#define C_QK   128
#define NH     8
#define H_     96
#define W_     96
#define NQ     (H_*W_)          // 9216
#define HD     48
#define WD     48
#define NK     (HD*WD)          // 2304
#define DQ     16
#define DV     32
#define NQC    (NQ/32)          // 288 query chunks
#define NKC    (NK/32)          // 72 key chunks
#define QPAIRS (NQC/2)          // 144
#define KQRT   (NKC/4)          // 18 key chunks per wave
#define KSTEPS (C_IN/16)        // 16 MFMA k-steps per GEMM
#define QS     0.3606737602222409f   // 0.25 * log2(e)

typedef __attribute__((ext_vector_type(8)))  short short8v;
typedef __attribute__((ext_vector_type(16))) float f32x16;
typedef __attribute__((ext_vector_type(2)))  int   v2i;

union B8u { uint u[4]; short8v v; };

static __device__ inline ushort bf16r(float f) {
    __hip_bfloat16 h = __float2bfloat16(f);
    return *reinterpret_cast<ushort*>(&h);
}
static __device__ inline uint cvtpk(float lo, float hi) {
    uint r;
    asm("v_cvt_pk_bf16_f32 %0, %1, %2" : "=v"(r) : "v"(lo), "v"(hi));
    return r;
}
static __device__ inline void lswap(uint a, uint b, uint& x, uint& y, int hi) {
#if __has_builtin(__builtin_amdgcn_permlane32_swap)
    v2i r = __builtin_amdgcn_permlane32_swap((int)a, (int)b, false, false);
    x = (uint)r.x;
    y = (uint)r.y;
#else
    uint bx = (uint)__shfl_xor((int)b, 32);
    uint ax = (uint)__shfl_xor((int)a, 32);
    x = hi ? bx : a;
    y = hi ? b : ax;
#endif
}
static __device__ inline float fexp2(float v) {
#if __has_builtin(__builtin_amdgcn_exp2f)
    return __builtin_amdgcn_exp2f(v);
#else
    return __expf(v * 0.6931471805599453f);
#endif
}

// ---------------- prep: pooled-x frag stream + packed weights ----------------
#define U_XPB  (NKC*KSTEPS*64)     // 73728
#define U_WQ   (4*KSTEPS*64)       // 4096
#define U_WK   (4*KSTEPS*64)       // 4096
#define U_WV   (8*KSTEPS*64)       // 8192
#define U_FRAG (U_XPB+U_WQ+U_WK+U_WV)
#define U_TOT  (U_FRAG + 128)

__global__ __launch_bounds__(256) void prep_kernel(
    const float* __restrict__ x,  const float* __restrict__ wq, const float* __restrict__ bq,
    const float* __restrict__ wk, const float* __restrict__ wv,
    ushort* __restrict__ xpbP,
    ushort* __restrict__ wqP, ushort* __restrict__ wkP, ushort* __restrict__ wvP,
    float* __restrict__ bqs)
{
    int t = blockIdx.x * 256 + threadIdx.x;
    if (t >= U_TOT) return;
    if (t >= U_FRAG) { int i = t - U_FRAG; bqs[i] = bq[i] * QS; return; }

    union { ushort s[8]; uint4 v; } ou;
    int u = t;
    if (u < U_XPB) {                             // maxpool(x) -> frag stream [72][16][64][8]
        int l = u & 63, rest = u >> 6;
        int ks = rest & 15, nc = rest >> 4;
        int np = nc * 32 + (l & 31);
        int k0 = ks * 16 + 8 * (l >> 5);
        int py = np / WD, px = np - py * WD;
        const float* base = x + (2 * py) * W_ + 2 * px;
        #pragma unroll
        for (int j = 0; j < 8; ++j) {
            const float* p = base + (size_t)(k0 + j) * NQ;
            ou.s[j] = bf16r(fmaxf(fmaxf(p[0], p[1]), fmaxf(p[W_], p[W_ + 1])));
        }
        *(uint4*)&xpbP[(size_t)u * 8] = ou.v;
        return;
    }
    u -= U_XPB;
    if (u < U_WQ) {
        int l = u & 63, ks = (u >> 6) & 15, mb = u >> 10;
        int m = mb * 32 + (l & 31), k0 = ks * 16 + 8 * (l >> 5);
        #pragma unroll
        for (int j = 0; j < 8; ++j) ou.s[j] = bf16r(wq[m * C_IN + k0 + j] * QS);
        *(uint4*)&wqP[(size_t)u * 8] = ou.v;
        return;
    }
    u -= U_WQ;
    if (u < U_WK) {
        int l = u & 63, ks = (u >> 6) & 15, mb = u >> 10;
        int m = mb * 32 + (l & 31), k0 = ks * 16 + 8 * (l >> 5);
        #pragma unroll
        for (int j = 0; j < 8; ++j) ou.s[j] = bf16r(wk[m * C_IN + k0 + j]);
        *(uint4*)&wkP[(size_t)u * 8] = ou.v;
        return;
    }
    u -= U_WK;
    {
        int l = u & 63, ks = (u >> 6) & 15, cb = u >> 10;
        int c = cb * 32 + (l & 31), k0 = ks * 16 + 8 * (l >> 5);
        #pragma unroll
        for (int j = 0; j < 8; ++j) ou.s[j] = bf16r(wv[c * C_IN + k0 + j]);
        *(uint4*)&wvP[(size_t)u * 8] = ou.v;
    }
}

// ---------------- shared GEMM pieces ----------------
static __device__ inline f32x16 mfma_loop(const ushort* __restrict__ A,
                                          const ushort* __restrict__ B) {
    f32x16 acc;
    #pragma unroll
    for (int r = 0; r < 16; ++r) acc[r] = 0.0f;
    #pragma unroll
    for (int s = 0; s < KSTEPS; ++s) {
        short8v a = *(const short8v*)(A + (size_t)s * 512);
        short8v b = *(const short8v*)(B + (size_t)s * 512);
        acc = __builtin_amdgcn_mfma_f32_32x32x16_bf16(a, b, acc, 0, 0, 0);
    }
    return acc;
}
static __device__ inline void xform(const f32x16& acc, int hi, short8v& F1, short8v& F2) {
    uint a0 = cvtpk(acc[0],  acc[1]),  a1 = cvtpk(acc[2],  acc[3]);
    uint b0 = cvtpk(acc[4],  acc[5]),  b1 = cvtpk(acc[6],  acc[7]);
    uint a2 = cvtpk(acc[8],  acc[9]),  a3 = cvtpk(acc[10], acc[11]);
    uint b2 = cvtpk(acc[12], acc[13]), b3 = cvtpk(acc[14], acc[15]);
    B8u f1, f2;
    lswap(a0, b0, f1.u[0], f1.u[2], hi);
    lswap(a1, b1, f1.u[1], f1.u[3], hi);
    lswap(a2, b2, f2.u[0], f2.u[2], hi);
    lswap(a3, b3, f2.u[1], f2.u[3], hi);
    F1 = f1.v; F2 = f2.v;
}

// -------- fused q/k/v GEMM: one 32x32 tile per wave --------
#define T_Q 1152            // 4 mb * 288 nc  (q reads x f32, converts inline)
#define T_K (T_Q + 288)     // + 4 mb * 72 nc
#define T_ALL (T_K + 576)   // + 8 cb * 72 kc

__global__ __launch_bounds__(256) void gemm_fused(
    const float* __restrict__ x, const ushort* __restrict__ xpbP,
    const ushort* __restrict__ wqP, const ushort* __restrict__ wkP,
    const ushort* __restrict__ wvP,
    const float* __restrict__ bqs, const float* __restrict__ bk,
    ushort* __restrict__ qpack, ushort* __restrict__ kpack, ushort* __restrict__ vpack)
{
    int lane = threadIdx.x & 63, wvi = threadIdx.x >> 6;
    int hi = lane >> 5;
    int t = blockIdx.x * 4 + wvi;
    if (t >= T_ALL) return;

    if (t < T_Q) {                               // q tile: rows 32*mb, cols 32*nc
        int mb = t / NQC, nc = t - mb * NQC;
        const ushort* A = wqP + ((size_t)(mb * KSTEPS) * 64 + lane) * 8;
        const float* xb = x + (size_t)(8 * hi) * NQ + nc * 32 + (lane & 31);
        f32x16 acc;
        #pragma unroll
        for (int r = 0; r < 16; ++r) acc[r] = 0.0f;
        #pragma unroll
        for (int s = 0; s < KSTEPS; ++s) {
            float f[8];
            #pragma unroll
            for (int j = 0; j < 8; ++j) f[j] = xb[(size_t)(s * 16 + j) * NQ];
            B8u bf;
            #pragma unroll
            for (int m = 0; m < 4; ++m) bf.u[m] = cvtpk(f[2 * m], f[2 * m + 1]);
            short8v a = *(const short8v*)(A + (size_t)s * 512);
            acc = __builtin_amdgcn_mfma_f32_32x32x16_bf16(a, bf.v, acc, 0, 0, 0);
        }
        #pragma unroll
        for (int r = 0; r < 16; ++r)
            acc[r] += bqs[mb * 32 + (r & 3) + 8 * (r >> 2) + 4 * hi];
        short8v F1, F2;
        xform(acc, hi, F1, F2);
        *(short8v*)&qpack[((size_t)((2 * mb)     * NQC + nc) * 64 + lane) * 8] = F1;
        *(short8v*)&qpack[((size_t)((2 * mb + 1) * NQC + nc) * 64 + lane) * 8] = F2;
    } else if (t < T_K) {                        // k tile
        int t2 = t - T_Q;
        int mb = t2 / NKC, nc = t2 - mb * NKC;
        const ushort* A = wkP  + ((size_t)(mb * KSTEPS) * 64 + lane) * 8;
        const ushort* B = xpbP + ((size_t)(nc * KSTEPS) * 64 + lane) * 8;
        f32x16 acc = mfma_loop(A, B);
        #pragma unroll
        for (int r = 0; r < 16; ++r)
            acc[r] += bk[mb * 32 + (r & 3) + 8 * (r >> 2) + 4 * hi];
        short8v F1, F2;
        xform(acc, hi, F1, F2);
        *(short8v*)&kpack[((size_t)((2 * mb)     * NKC + nc) * 64 + lane) * 8] = F1;
        *(short8v*)&kpack[((size_t)((2 * mb + 1) * NKC + nc) * 64 + lane) * 8] = F2;
    } else {                                     // v tile, transposed: C^T[key][c]
        int t3 = t - T_K;
        int cb = t3 / NKC, kc = t3 - cb * NKC;
        const ushort* A = xpbP + ((size_t)(kc * KSTEPS) * 64 + lane) * 8;
        const ushort* B = wvP  + ((size_t)(cb * KSTEPS) * 64 + lane) * 8;
        f32x16 acc = mfma_loop(A, B);
        short8v F1, F2;
        xform(acc, hi, F1, F2);
        *(short8v*)&vpack[((size_t)((cb * NKC + kc) * 2 + 0) * 64 + lane) * 8] = F1;
        *(short8v*)&vpack[((size_t)((cb * NKC + kc) * 2 + 1) * 64 + lane) * 8] = F2;
    }
}

// ---------------- fused attention: 64 q/wave, 4-way key split, half-split softmax ----------------
static __device__ inline void qstep(short8v kcur, short8v qf, short8v v0c, short8v v1c,
                                    f32x16& o, float& rs, const f32x16& zc, int hi) {
    f32x16 s = __builtin_amdgcn_mfma_f32_32x32x16_bf16(kcur, qf, zc, 0, 0, 0);
    // half 1: acc regs 0..7 (k rows 0..15) -> B1 -> PV with v0
    {
        float e0 = fexp2(s[0]), e1 = fexp2(s[1]), e2 = fexp2(s[2]), e3 = fexp2(s[3]);
        float e4 = fexp2(s[4]), e5 = fexp2(s[5]), e6 = fexp2(s[6]), e7 = fexp2(s[7]);
        rs += ((e0 + e1) + (e2 + e3)) + ((e4 + e5) + (e6 + e7));
        uint a0 = cvtpk(e0, e1), a1 = cvtpk(e2, e3);
        uint b0 = cvtpk(e4, e5), b1 = cvtpk(e6, e7);
        B8u B1;
        lswap(a0, b0, B1.u[0], B1.u[2], hi);
        lswap(a1, b1, B1.u[1], B1.u[3], hi);
        o = __builtin_amdgcn_mfma_f32_32x32x16_bf16(v0c, B1.v, o, 0, 0, 0);
    }
    // half 2: acc regs 8..15 (k rows 16..31) -> B2 -> PV with v1
    {
        float e0 = fexp2(s[8]),  e1 = fexp2(s[9]),  e2 = fexp2(s[10]), e3 = fexp2(s[11]);
        float e4 = fexp2(s[12]), e5 = fexp2(s[13]), e6 = fexp2(s[14]), e7 = fexp2(s[15]);
        rs += ((e0 + e1) + (e2 + e3)) + ((e4 + e5) + (e6 + e7));
        uint a0 = cvtpk(e0, e1), a1 = cvtpk(e2, e3);
        uint b0 = cvtpk(e4, e5), b1 = cvtpk(e6, e7);
        B8u B2;
        lswap(a0, b0, B2.u[0], B2.u[2], hi);
        lswap(a1, b1, B2.u[1], B2.u[3], hi);
        o = __builtin_amdgcn_mfma_f32_32x32x16_bf16(v1c, B2.v, o, 0, 0, 0);
    }
}

__global__ __launch_bounds__(256) void attn_kernel(const ushort* __restrict__ qpack,
                                                   const ushort* __restrict__ kpack,
                                                   const ushort* __restrict__ vpack,
                                                   const float* __restrict__ x,
                                                   float* __restrict__ out) {
    __shared__ float part[4][2][64][20];   // 40 KB
    const int h = blockIdx.y;
    const int tid = threadIdx.x, lane = tid & 63;
    const int kh = tid >> 6;               // key quarter 0..3
    const int q31 = lane & 31, hi = lane >> 5;
    const int qp = blockIdx.x;

    short8v qf0 = *(const short8v*)&qpack[((size_t)(h * NQC + 2 * qp)     * 64 + lane) * 8];
    short8v qf1 = *(const short8v*)&qpack[((size_t)(h * NQC + 2 * qp + 1) * 64 + lane) * 8];

    const ushort* kp = kpack + ((size_t)(h * NKC + kh * KQRT) * 64 + lane) * 8;
    const ushort* vp = vpack + ((size_t)(h * NKC + kh * KQRT) * 2 * 64 + lane) * 8;

    short8v kf = *(const short8v*)kp;          // prefetch k
    short8v v0 = *(const short8v*)vp;          // prefetch v half 0

    f32x16 o0, o1, zc;
    #pragma unroll
    for (int r = 0; r < 16; ++r) { o0[r] = 0.0f; o1[r] = 0.0f; zc[r] = 0.0f; }
    float rs0 = 0.0f, rs1 = 0.0f;

    for (int c = 0; c < KQRT; ++c) {
        short8v kcur = kf, v0c = v0;
        short8v v1c = *(const short8v*)(vp + (size_t)c * 1024 + 512);  // used ~250cy later
        int cn = (c == KQRT - 1) ? 0 : (c + 1);     // wrap: in-bounds, data unused
        kf = *(const short8v*)(kp + (size_t)cn * 512);
        v0 = *(const short8v*)(vp + (size_t)cn * 1024);

        qstep(kcur, qf0, v0c, v1c, o0, rs0, zc, hi);
        qstep(kcur, qf1, v0c, v1c, o1, rs1, zc, hi);
    }

    rs0 += __shfl_xor(rs0, 32);
    rs1 += __shfl_xor(rs1, 32);

    {
        float* p0 = &part[kh][0][lane][0];
        #pragma unroll
        for (int i = 0; i < 4; ++i)
            *(float4*)&p0[4 * i] = *(float4*)((const float*)&o0 + 4 * i);
        p0[16] = rs0;
        float* p1 = &part[kh][1][lane][0];
        #pragma unroll
        for (int i = 0; i < 4; ++i)
            *(float4*)&p1[4 * i] = *(float4*)((const float*)&o1 + 4 * i);
        p1[16] = rs1;
    }
    __syncthreads();

    if (kh < 2) {   // wave kh finalizes q-frag kh
        float o[16] = {};
        float rs = 0.0f;
        #pragma unroll
        for (int w = 0; w < 4; ++w) {
            const float* pw = &part[w][kh][lane][0];
            #pragma unroll
            for (int i = 0; i < 4; ++i) {
                float4 f = *(const float4*)&pw[4 * i];
                o[4 * i + 0] += f.x; o[4 * i + 1] += f.y;
                o[4 * i + 2] += f.z; o[4 * i + 3] += f.w;
            }
            rs += pw[16];
        }
        float inv = 1.0f / rs;
        int q = (2 * qp + kh) * 32 + q31;
        #pragma unroll
        for (int r = 0; r < 16; ++r) {
            int dv = (r & 3) + 8 * (r >> 2) + 4 * hi;
            size_t i0 = (size_t)(h * DV + dv) * NQ + q;
            out[i0] = o[r] * inv + x[i0];
        }
    }
}

// ---------------- launcher ----------------
extern "C" void kernel_launch(void* const* d_in, const int* in_sizes, int n_in,
                              void* d_out, int out_size, void* d_ws, size_t ws_size,
                              hipStream_t stream) {
    const float* x  = (const float*)d_in[0];
    const float* wq = (const float*)d_in[1];
    const float* bq = (const float*)d_in[2];
    const float* wk = (const float*)d_in[3];
    const float* bk = (const float*)d_in[4];
    const float* wv = (const float*)d_in[5];
    float* out = (float*)d_out;

    ushort* p = (ushort*)d_ws;
    ushort* xpbP  = p;  p += (size_t)U_XPB * 8;
    ushort* wqP   = p;  p += (size_t)U_WQ  * 8;
    ushort* wkP   = p;  p += (size_t)U_WK  * 8;
    ushort* wvP   = p;  p += (size_t)U_WV  * 8;
    ushort* qpack = p;  p += (size_t)NH * NQC * 64 * 8;
    ushort* kpack = p;  p += (size_t)NH * NKC * 64 * 8;
    ushort* vpack = p;  p += (size_t)NH * NKC * 2 * 64 * 8;
    float*  bqs   = (float*)p;

    prep_kernel<<<(U_TOT + 255) / 256, 256, 0, stream>>>(x, wq, bq, wk, wv,
                                                         xpbP, wqP, wkP, wvP, bqs);
    gemm_fused<<<(T_ALL + 3) / 4, 256, 0, stream>>>(x, xpbP, wqP, wkP, wvP,
                                                    bqs, bk, qpack, kpack, vpack);
    attn_kernel<<<dim3(QPAIRS, NH), 256, 0, stream>>>(qpack, kpack, vpack, x, out);
}

// Round 7
// 114.581 us; speedup vs baseline: 1.0166x; 1.0166x over previous
//
#include <hip/hip_runtime.h>
#include <hip/hip_bf16.h>
#include <math.h>

// Problem constants
#define C_IN   256
#define C_QK   128
#define NH     8
#define H_     96
#define W_     96
#define NQ     (H_*W_)          // 9216
#define HD     48
#define WD     48
#define NK     (HD*WD)          // 2304
#define DQ     16
#define DV     32
#define NQC    (NQ/32)          // 288 query chunks
#define NKC    (NK/32)          // 72 key chunks
#define KQRT   (NKC/4)          // 18 key chunks per wave
#define KSTEPS (C_IN/16)        // 16 MFMA k-steps per GEMM
#define QS     0.3606737602222409f   // 0.25 * log2(e)

typedef __attribute__((ext_vector_type(8)))  short short8v;
typedef __attribute__((ext_vector_type(16))) float f32x16;
typedef __attribute__((ext_vector_type(2)))  int   v2i;

union B8u { uint u[4]; short8v v; };

static __device__ inline ushort bf16r(float f) {
    __hip_bfloat16 h = __float2bfloat16(f);
    return *reinterpret_cast<ushort*>(&h);
}
static __device__ inline uint cvtpk(float lo, float hi) {
    uint r;
    asm("v_cvt_pk_bf16_f32 %0, %1, %2" : "=v"(r) : "v"(lo), "v"(hi));
    return r;
}
static __device__ inline void lswap(uint a, uint b, uint& x, uint& y, int hi) {
#if __has_builtin(__builtin_amdgcn_permlane32_swap)
    v2i r = __builtin_amdgcn_permlane32_swap((int)a, (int)b, false, false);
    x = (uint)r.x;
    y = (uint)r.y;
#else
    uint bx = (uint)__shfl_xor((int)b, 32);
    uint ax = (uint)__shfl_xor((int)a, 32);
    x = hi ? bx : a;
    y = hi ? b : ax;
#endif
}
static __device__ inline float fexp2(float v) {
#if __has_builtin(__builtin_amdgcn_exp2f)
    return __builtin_amdgcn_exp2f(v);
#else
    return __expf(v * 0.6931471805599453f);
#endif
}

// ---------------- prep: pack x, pooled-x, weights into MFMA fragment streams ----------------
#define U_XB   (NQC*KSTEPS*64)     // 294912
#define U_XPB  (NKC*KSTEPS*64)     // 73728
#define U_WQ   (4*KSTEPS*64)       // 4096
#define U_WK   (4*KSTEPS*64)       // 4096
#define U_WV   (8*KSTEPS*64)       // 8192
#define U_FRAG (U_XB+U_XPB+U_WQ+U_WK+U_WV)
#define U_TOT  (U_FRAG + 128)

__global__ __launch_bounds__(256) void prep_kernel(
    const float* __restrict__ x,  const float* __restrict__ wq, const float* __restrict__ bq,
    const float* __restrict__ wk, const float* __restrict__ wv,
    ushort* __restrict__ xbP, ushort* __restrict__ xpbP,
    ushort* __restrict__ wqP, ushort* __restrict__ wkP, ushort* __restrict__ wvP,
    float* __restrict__ bqs)
{
    int t = blockIdx.x * 256 + threadIdx.x;
    if (t >= U_TOT) return;
    if (t >= U_FRAG) { int i = t - U_FRAG; bqs[i] = bq[i] * QS; return; }

    union { ushort s[8]; uint4 v; } ou;
    int u = t;
    if (u < U_XB) {                              // x -> B-frag stream [288][16][64][8]
        int l = u & 63, rest = u >> 6;
        int ks = rest & 15, nc = rest >> 4;
        int n  = nc * 32 + (l & 31);
        int k0 = ks * 16 + 8 * (l >> 5);
        #pragma unroll
        for (int j = 0; j < 8; ++j) ou.s[j] = bf16r(x[(size_t)(k0 + j) * NQ + n]);
        *(uint4*)&xbP[(size_t)u * 8] = ou.v;
        return;
    }
    u -= U_XB;
    if (u < U_XPB) {                             // maxpool(x) -> frag stream [72][16][64][8]
        int l = u & 63, rest = u >> 6;
        int ks = rest & 15, nc = rest >> 4;
        int np = nc * 32 + (l & 31);
        int k0 = ks * 16 + 8 * (l >> 5);
        int py = np / WD, px = np - py * WD;
        const float* base = x + (2 * py) * W_ + 2 * px;
        #pragma unroll
        for (int j = 0; j < 8; ++j) {
            const float* p = base + (size_t)(k0 + j) * NQ;
            ou.s[j] = bf16r(fmaxf(fmaxf(p[0], p[1]), fmaxf(p[W_], p[W_ + 1])));
        }
        *(uint4*)&xpbP[(size_t)u * 8] = ou.v;
        return;
    }
    u -= U_XPB;
    if (u < U_WQ) {
        int l = u & 63, ks = (u >> 6) & 15, mb = u >> 10;
        int m = mb * 32 + (l & 31), k0 = ks * 16 + 8 * (l >> 5);
        #pragma unroll
        for (int j = 0; j < 8; ++j) ou.s[j] = bf16r(wq[m * C_IN + k0 + j] * QS);
        *(uint4*)&wqP[(size_t)u * 8] = ou.v;
        return;
    }
    u -= U_WQ;
    if (u < U_WK) {
        int l = u & 63, ks = (u >> 6) & 15, mb = u >> 10;
        int m = mb * 32 + (l & 31), k0 = ks * 16 + 8 * (l >> 5);
        #pragma unroll
        for (int j = 0; j < 8; ++j) ou.s[j] = bf16r(wk[m * C_IN + k0 + j]);
        *(uint4*)&wkP[(size_t)u * 8] = ou.v;
        return;
    }
    u -= U_WK;
    {
        int l = u & 63, ks = (u >> 6) & 15, cb = u >> 10;
        int c = cb * 32 + (l & 31), k0 = ks * 16 + 8 * (l >> 5);
        #pragma unroll
        for (int j = 0; j < 8; ++j) ou.s[j] = bf16r(wv[c * C_IN + k0 + j]);
        *(uint4*)&wvP[(size_t)u * 8] = ou.v;
    }
}

// ---------------- shared GEMM pieces ----------------
static __device__ inline f32x16 mfma_loop(const ushort* __restrict__ A,
                                          const ushort* __restrict__ B) {
    f32x16 acc;
    #pragma unroll
    for (int r = 0; r < 16; ++r) acc[r] = 0.0f;
    #pragma unroll
    for (int s = 0; s < KSTEPS; ++s) {
        short8v a = *(const short8v*)(A + (size_t)s * 512);
        short8v b = *(const short8v*)(B + (size_t)s * 512);
        acc = __builtin_amdgcn_mfma_f32_32x32x16_bf16(a, b, acc, 0, 0, 0);
    }
    return acc;
}
static __device__ inline void xform(const f32x16& acc, int hi, short8v& F1, short8v& F2) {
    uint a0 = cvtpk(acc[0],  acc[1]),  a1 = cvtpk(acc[2],  acc[3]);
    uint b0 = cvtpk(acc[4],  acc[5]),  b1 = cvtpk(acc[6],  acc[7]);
    uint a2 = cvtpk(acc[8],  acc[9]),  a3 = cvtpk(acc[10], acc[11]);
    uint b2 = cvtpk(acc[12], acc[13]), b3 = cvtpk(acc[14], acc[15]);
    B8u f1, f2;
    lswap(a0, b0, f1.u[0], f1.u[2], hi);
    lswap(a1, b1, f1.u[1], f1.u[3], hi);
    lswap(a2, b2, f2.u[0], f2.u[2], hi);
    lswap(a3, b3, f2.u[1], f2.u[3], hi);
    F1 = f1.v; F2 = f2.v;
}

// -------- fused q/k/v GEMM: one 32x32 tile per wave, 2016 tiles flat --------
#define T_Q 1152            // 4 mb * 288 nc
#define T_K (T_Q + 288)     // + 4 mb * 72 nc
#define T_ALL (T_K + 576)   // + 8 cb * 72 kc

__global__ __launch_bounds__(256) void gemm_fused(
    const ushort* __restrict__ xbP, const ushort* __restrict__ xpbP,
    const ushort* __restrict__ wqP, const ushort* __restrict__ wkP,
    const ushort* __restrict__ wvP,
    const float* __restrict__ bqs, const float* __restrict__ bk,
    ushort* __restrict__ qpack, ushort* __restrict__ kpack, ushort* __restrict__ vpack)
{
    int lane = threadIdx.x & 63, wvi = threadIdx.x >> 6;
    int hi = lane >> 5;
    int t = blockIdx.x * 4 + wvi;
    if (t >= T_ALL) return;

    if (t < T_Q) {
        int mb = t / NQC, nc = t - mb * NQC;
        const ushort* A = wqP + ((size_t)(mb * KSTEPS) * 64 + lane) * 8;
        const ushort* B = xbP + ((size_t)(nc * KSTEPS) * 64 + lane) * 8;
        f32x16 acc = mfma_loop(A, B);
        #pragma unroll
        for (int r = 0; r < 16; ++r)
            acc[r] += bqs[mb * 32 + (r & 3) + 8 * (r >> 2) + 4 * hi];
        short8v F1, F2;
        xform(acc, hi, F1, F2);
        *(short8v*)&qpack[((size_t)((2 * mb)     * NQC + nc) * 64 + lane) * 8] = F1;
        *(short8v*)&qpack[((size_t)((2 * mb + 1) * NQC + nc) * 64 + lane) * 8] = F2;
    } else if (t < T_K) {
        int t2 = t - T_Q;
        int mb = t2 / NKC, nc = t2 - mb * NKC;
        const ushort* A = wkP  + ((size_t)(mb * KSTEPS) * 64 + lane) * 8;
        const ushort* B = xpbP + ((size_t)(nc * KSTEPS) * 64 + lane) * 8;
        f32x16 acc = mfma_loop(A, B);
        #pragma unroll
        for (int r = 0; r < 16; ++r)
            acc[r] += bk[mb * 32 + (r & 3) + 8 * (r >> 2) + 4 * hi];
        short8v F1, F2;
        xform(acc, hi, F1, F2);
        *(short8v*)&kpack[((size_t)((2 * mb)     * NKC + nc) * 64 + lane) * 8] = F1;
        *(short8v*)&kpack[((size_t)((2 * mb + 1) * NKC + nc) * 64 + lane) * 8] = F2;
    } else {                                     // v, transposed: C^T[key][c]
        int t3 = t - T_K;
        int cb = t3 / NKC, kc = t3 - cb * NKC;
        const ushort* A = xpbP + ((size_t)(kc * KSTEPS) * 64 + lane) * 8;
        const ushort* B = wvP  + ((size_t)(cb * KSTEPS) * 64 + lane) * 8;
        f32x16 acc = mfma_loop(A, B);
        short8v F1, F2;
        xform(acc, hi, F1, F2);
        *(short8v*)&vpack[((size_t)((cb * NKC + kc) * 2 + 0) * 64 + lane) * 8] = F1;
        *(short8v*)&vpack[((size_t)((cb * NKC + kc) * 2 + 1) * 64 + lane) * 8] = F2;
    }
}

// ---------------- fused attention: 32 q/wave, block = 4 key-quarters of one q-chunk ----------------
#define CSTR 17   // LDS combine row stride (floats): gcd(17,32)=1 -> conflict-free scalar

__global__ __launch_bounds__(256) void attn_kernel(const ushort* __restrict__ qpack,
                                                   const ushort* __restrict__ kpack,
                                                   const ushort* __restrict__ vpack,
                                                   const float* __restrict__ x,
                                                   float* __restrict__ out) {
    __shared__ float part[4][64][CSTR];    // 17.4 KB
    const int h = blockIdx.y, qc = blockIdx.x;
    const int tid = threadIdx.x, lane = tid & 63;
    const int kh = tid >> 6;               // key quarter 0..3
    const int q31 = lane & 31, hi = lane >> 5;

    short8v qf = *(const short8v*)&qpack[((size_t)(h * NQC + qc) * 64 + lane) * 8];

    const ushort* kp = kpack + ((size_t)(h * NKC + kh * KQRT) * 64 + lane) * 8;
    const ushort* vp = vpack + ((size_t)(h * NKC + kh * KQRT) * 2 * 64 + lane) * 8;

    short8v kf = *(const short8v*)kp;          // prefetch k
    short8v v0 = *(const short8v*)vp;          // prefetch v half 0

    f32x16 o, zc;
    #pragma unroll
    for (int r = 0; r < 16; ++r) { o[r] = 0.0f; zc[r] = 0.0f; }
    float rs = 0.0f;

    for (int c = 0; c < KQRT; ++c) {
        short8v kcur = kf, v0c = v0;
        short8v v1c = *(const short8v*)(vp + (size_t)c * 1024 + 512);  // used after half 1
        int cn = (c == KQRT - 1) ? 0 : (c + 1);     // wrap: in-bounds, data unused
        kf = *(const short8v*)(kp + (size_t)cn * 512);
        v0 = *(const short8v*)(vp + (size_t)cn * 1024);

        f32x16 s = __builtin_amdgcn_mfma_f32_32x32x16_bf16(kcur, qf, zc, 0, 0, 0);
        // half 1: acc regs 0..7 (k rows 0..15) -> PV with v0
        {
            float e0 = fexp2(s[0]), e1 = fexp2(s[1]), e2 = fexp2(s[2]), e3 = fexp2(s[3]);
            float e4 = fexp2(s[4]), e5 = fexp2(s[5]), e6 = fexp2(s[6]), e7 = fexp2(s[7]);
            rs += ((e0 + e1) + (e2 + e3)) + ((e4 + e5) + (e6 + e7));
            uint a0 = cvtpk(e0, e1), a1 = cvtpk(e2, e3);
            uint b0 = cvtpk(e4, e5), b1 = cvtpk(e6, e7);
            B8u B1;
            lswap(a0, b0, B1.u[0], B1.u[2], hi);
            lswap(a1, b1, B1.u[1], B1.u[3], hi);
            o = __builtin_amdgcn_mfma_f32_32x32x16_bf16(v0c, B1.v, o, 0, 0, 0);
        }
        // half 2: acc regs 8..15 (k rows 16..31) -> PV with v1
        {
            float e0 = fexp2(s[8]),  e1 = fexp2(s[9]),  e2 = fexp2(s[10]), e3 = fexp2(s[11]);
            float e4 = fexp2(s[12]), e5 = fexp2(s[13]), e6 = fexp2(s[14]), e7 = fexp2(s[15]);
            rs += ((e0 + e1) + (e2 + e3)) + ((e4 + e5) + (e6 + e7));
            uint a0 = cvtpk(e0, e1), a1 = cvtpk(e2, e3);
            uint b0 = cvtpk(e4, e5), b1 = cvtpk(e6, e7);
            B8u B2;
            lswap(a0, b0, B2.u[0], B2.u[2], hi);
            lswap(a1, b1, B2.u[1], B2.u[3], hi);
            o = __builtin_amdgcn_mfma_f32_32x32x16_bf16(v1c, B2.v, o, 0, 0, 0);
        }
    }

    rs += __shfl_xor(rs, 32);

    {
        float* pw = &part[kh][lane][0];
        #pragma unroll
        for (int r = 0; r < 16; ++r) pw[r] = o[r];
        pw[16] = rs;
    }
    __syncthreads();

    // all 4 waves combine: wave kh handles acc rows 4*kh .. 4*kh+3
    float rsAll = part[0][lane][16] + part[1][lane][16]
                + part[2][lane][16] + part[3][lane][16];
    float inv = 1.0f / rsAll;
    int q = qc * 32 + q31;
    #pragma unroll
    for (int i = 0; i < 4; ++i) {
        int r = 4 * kh + i;
        float val = part[0][lane][r] + part[1][lane][r]
                  + part[2][lane][r] + part[3][lane][r];
        int dv = i + 8 * kh + 4 * hi;          // == (r&3) + 8*(r>>2) + 4*hi
        size_t i0 = (size_t)(h * DV + dv) * NQ + q;
        out[i0] = val * inv + x[i0];
    }
}

// ---------------- launcher ----------------
extern "C" void kernel_launch(void* const* d_in, const int* in_sizes, int n_in,
                              void* d_out, int out_size, void* d_ws, size_t ws_size,
                              hipStream_t stream) {
    const float* x  = (const float*)d_in[0];
    const float* wq = (const float*)d_in[1];
    const float* bq = (const float*)d_in[2];
    const float* wk = (const float*)d_in[3];
    const float* bk = (const float*)d_in[4];
    const float* wv = (const float*)d_in[5];
    float* out = (float*)d_out;

    ushort* p = (ushort*)d_ws;
    ushort* xbP   = p;  p += (size_t)U_XB  * 8;
    ushort* xpbP  = p;  p += (size_t)U_XPB * 8;
    ushort* wqP   = p;  p += (size_t)U_WQ  * 8;
    ushort* wkP   = p;  p += (size_t)U_WK  * 8;
    ushort* wvP   = p;  p += (size_t)U_WV  * 8;
    ushort* qpack = p;  p += (size_t)NH * NQC * 64 * 8;
    ushort* kpack = p;  p += (size_t)NH * NKC * 64 * 8;
    ushort* vpack = p;  p += (size_t)NH * NKC * 2 * 64 * 8;
    float*  bqs   = (float*)p;

    prep_kernel<<<(U_TOT + 255) / 256, 256, 0, stream>>>(x, wq, bq, wk, wv,
                                                         xbP, xpbP, wqP, wkP, wvP, bqs);
    gemm_fused<<<(T_ALL + 3) / 4, 256, 0, stream>>>(xbP, xpbP, wqP, wkP, wvP,
                                                    bqs, bk, qpack, kpack, vpack);
    attn_kernel<<<dim3(NQC, NH), 256, 0, stream>>>(qpack, kpack, vpack, x, out);
}

// Round 8
// 111.893 us; speedup vs baseline: 1.0410x; 1.0240x over previous
//
#include <hip/hip_runtime.h>
#include <hip/hip_bf16.h>
#include <math.h>

// Problem constants
#define C_IN   256
#define C_QK   128
#define NH     8
#define H_     96
#define W_     96
#define NQ     (H_*W_)          // 9216
#define HD     48
#define WD     48
#define NK     (HD*WD)          // 2304
#define DQ     16
#define DV     32
#define NQC    (NQ/32)          // 288 query chunks
#define NKC    (NK/32)          // 72 key chunks
#define KQRT   (NKC/4)          // 18 key chunks per wave
#define KSTEPS (C_IN/16)        // 16 MFMA k-steps per GEMM
#define QS     0.3606737602222409f   // 0.25 * log2(e)

typedef __attribute__((ext_vector_type(8)))  short short8v;
typedef __attribute__((ext_vector_type(16))) float f32x16;
typedef __attribute__((ext_vector_type(2)))  int   v2i;

union B8u { uint u[4]; short8v v; };

static __device__ inline uint cvtpk(float lo, float hi) {
    uint r;
    asm("v_cvt_pk_bf16_f32 %0, %1, %2" : "=v"(r) : "v"(lo), "v"(hi));
    return r;
}
static __device__ inline void lswap(uint a, uint b, uint& x, uint& y, int hi) {
#if __has_builtin(__builtin_amdgcn_permlane32_swap)
    v2i r = __builtin_amdgcn_permlane32_swap((int)a, (int)b, false, false);
    x = (uint)r.x;
    y = (uint)r.y;
#else
    uint bx = (uint)__shfl_xor((int)b, 32);
    uint ax = (uint)__shfl_xor((int)a, 32);
    x = hi ? bx : a;
    y = hi ? b : ax;
#endif
}
static __device__ inline float fexp2(float v) {
#if __has_builtin(__builtin_amdgcn_exp2f)
    return __builtin_amdgcn_exp2f(v);
#else
    return __expf(v * 0.6931471805599453f);
#endif
}

// -------- fused prep+GEMM: 504 blocks --------
// q-blocks [0,288): stage x[:,32nc..] f32->bf16 frags in LDS; 4 waves = 4 mb-tiles
// k-blocks [288,360): stage maxpool tile; 4 waves = 4 mb-tiles
// v-blocks [360,504): stage maxpool tile (2 blocks/kc); 4 waves = 4 cb-tiles
#define GQ_B 288
#define GK_B (GQ_B + 72)
#define G_ALL (GK_B + 144)

__global__ __launch_bounds__(256) void gemm_all(
    const float* __restrict__ x,
    const float* __restrict__ wq, const float* __restrict__ bq,
    const float* __restrict__ wk, const float* __restrict__ bk_,
    const float* __restrict__ wv,
    ushort* __restrict__ qpack, ushort* __restrict__ kpack, ushort* __restrict__ vpack)
{
    __shared__ ushort Bf[KSTEPS][64][8];   // 16 KB: frag(s, lane) = 8 bf16
    const int tid = threadIdx.x, lane = tid & 63, wvi = tid >> 6;
    const int hi = lane >> 5;
    const int bid = blockIdx.x;

    // ---- stage B-frag tile into LDS (all 256 threads) ----
    {
        int c = tid & 31;             // column within 32-chunk
        int ko0 = (tid >> 5) * 4;     // 4 channel-octets per thread
        if (bid < GQ_B) {
            int col = bid * 32 + c;
            #pragma unroll
            for (int u = 0; u < 4; ++u) {
                int ko = ko0 + u;
                const float* xp_ = x + (size_t)(8 * ko) * NQ + col;
                float f[8];
                #pragma unroll
                for (int j = 0; j < 8; ++j) f[j] = xp_[(size_t)j * NQ];
                uint4 w;
                w.x = cvtpk(f[0], f[1]); w.y = cvtpk(f[2], f[3]);
                w.z = cvtpk(f[4], f[5]); w.w = cvtpk(f[6], f[7]);
                *(uint4*)&Bf[ko >> 1][32 * (ko & 1) + c][0] = w;
            }
        } else {
            int kc = (bid < GK_B) ? (bid - GQ_B) : ((bid - GK_B) >> 1);
            int np = kc * 32 + c;
            int py = np / WD, px = np - py * WD;
            const float* base = x + (2 * py) * W_ + 2 * px;
            #pragma unroll
            for (int u = 0; u < 4; ++u) {
                int ko = ko0 + u;
                const float* xp_ = base + (size_t)(8 * ko) * NQ;
                float f[8];
                #pragma unroll
                for (int j = 0; j < 8; ++j) {
                    const float* p = xp_ + (size_t)j * NQ;
                    f[j] = fmaxf(fmaxf(p[0], p[1]), fmaxf(p[W_], p[W_ + 1]));
                }
                uint4 w;
                w.x = cvtpk(f[0], f[1]); w.y = cvtpk(f[2], f[3]);
                w.z = cvtpk(f[4], f[5]); w.w = cvtpk(f[6], f[7]);
                *(uint4*)&Bf[ko >> 1][32 * (ko & 1) + c][0] = w;
            }
        }
    }
    __syncthreads();

    // ---- compute: each wave owns one 32x32 output tile ----
    f32x16 acc;
    #pragma unroll
    for (int r = 0; r < 16; ++r) acc[r] = 0.0f;

    const float* Wsrc;
    if (bid < GQ_B)      Wsrc = wq + (size_t)(wvi * 32 + (lane & 31)) * C_IN + 8 * hi;
    else if (bid < GK_B) Wsrc = wk + (size_t)(wvi * 32 + (lane & 31)) * C_IN + 8 * hi;
    else {
        int cb = ((bid - GK_B) & 1) * 4 + wvi;
        Wsrc = wv + (size_t)(cb * 32 + (lane & 31)) * C_IN + 8 * hi;
    }

    #pragma unroll
    for (int s = 0; s < KSTEPS; ++s) {
        float4 wa = *(const float4*)(Wsrc + 16 * s);
        float4 wb = *(const float4*)(Wsrc + 16 * s + 4);
        B8u af;
        af.u[0] = cvtpk(wa.x, wa.y); af.u[1] = cvtpk(wa.z, wa.w);
        af.u[2] = cvtpk(wb.x, wb.y); af.u[3] = cvtpk(wb.z, wb.w);
        short8v b = *(const short8v*)&Bf[s][lane][0];
        if (bid < GK_B)
            acc = __builtin_amdgcn_mfma_f32_32x32x16_bf16(af.v, b, acc, 0, 0, 0);
        else  // v-path: pooled tile is the A-operand (rows = keys), weights are B
            acc = __builtin_amdgcn_mfma_f32_32x32x16_bf16(b, af.v, acc, 0, 0, 0);
    }

    short8v F1, F2;
    if (bid < GQ_B) {                       // (acc + bq) * QS
        int nc = bid, mb = wvi;
        #pragma unroll
        for (int r = 0; r < 16; ++r)
            acc[r] = (acc[r] + bq[mb * 32 + (r & 3) + 8 * (r >> 2) + 4 * hi]) * QS;
        {
            uint a0 = cvtpk(acc[0],  acc[1]),  a1 = cvtpk(acc[2],  acc[3]);
            uint b0 = cvtpk(acc[4],  acc[5]),  b1 = cvtpk(acc[6],  acc[7]);
            uint a2 = cvtpk(acc[8],  acc[9]),  a3 = cvtpk(acc[10], acc[11]);
            uint b2 = cvtpk(acc[12], acc[13]), b3 = cvtpk(acc[14], acc[15]);
            B8u f1, f2;
            lswap(a0, b0, f1.u[0], f1.u[2], hi);
            lswap(a1, b1, f1.u[1], f1.u[3], hi);
            lswap(a2, b2, f2.u[0], f2.u[2], hi);
            lswap(a3, b3, f2.u[1], f2.u[3], hi);
            F1 = f1.v; F2 = f2.v;
        }
        *(short8v*)&qpack[((size_t)((2 * mb)     * NQC + nc) * 64 + lane) * 8] = F1;
        *(short8v*)&qpack[((size_t)((2 * mb + 1) * NQC + nc) * 64 + lane) * 8] = F2;
    } else if (bid < GK_B) {                // acc + bk
        int nc = bid - GQ_B, mb = wvi;
        #pragma unroll
        for (int r = 0; r < 16; ++r)
            acc[r] += bk_[mb * 32 + (r & 3) + 8 * (r >> 2) + 4 * hi];
        {
            uint a0 = cvtpk(acc[0],  acc[1]),  a1 = cvtpk(acc[2],  acc[3]);
            uint b0 = cvtpk(acc[4],  acc[5]),  b1 = cvtpk(acc[6],  acc[7]);
            uint a2 = cvtpk(acc[8],  acc[9]),  a3 = cvtpk(acc[10], acc[11]);
            uint b2 = cvtpk(acc[12], acc[13]), b3 = cvtpk(acc[14], acc[15]);
            B8u f1, f2;
            lswap(a0, b0, f1.u[0], f1.u[2], hi);
            lswap(a1, b1, f1.u[1], f1.u[3], hi);
            lswap(a2, b2, f2.u[0], f2.u[2], hi);
            lswap(a3, b3, f2.u[1], f2.u[3], hi);
            F1 = f1.v; F2 = f2.v;
        }
        *(short8v*)&kpack[((size_t)((2 * mb)     * NKC + nc) * 64 + lane) * 8] = F1;
        *(short8v*)&kpack[((size_t)((2 * mb + 1) * NKC + nc) * 64 + lane) * 8] = F2;
    } else {                                // v: C^T[key][c], no bias
        int vb = bid - GK_B;
        int kc = vb >> 1, cb = (vb & 1) * 4 + wvi;
        {
            uint a0 = cvtpk(acc[0],  acc[1]),  a1 = cvtpk(acc[2],  acc[3]);
            uint b0 = cvtpk(acc[4],  acc[5]),  b1 = cvtpk(acc[6],  acc[7]);
            uint a2 = cvtpk(acc[8],  acc[9]),  a3 = cvtpk(acc[10], acc[11]);
            uint b2 = cvtpk(acc[12], acc[13]), b3 = cvtpk(acc[14], acc[15]);
            B8u f1, f2;
            lswap(a0, b0, f1.u[0], f1.u[2], hi);
            lswap(a1, b1, f1.u[1], f1.u[3], hi);
            lswap(a2, b2, f2.u[0], f2.u[2], hi);
            lswap(a3, b3, f2.u[1], f2.u[3], hi);
            F1 = f1.v; F2 = f2.v;
        }
        *(short8v*)&vpack[((size_t)((cb * NKC + kc) * 2 + 0) * 64 + lane) * 8] = F1;
        *(short8v*)&vpack[((size_t)((cb * NKC + kc) * 2 + 1) * 64 + lane) * 8] = F2;
    }
}

// ---------------- fused attention ----------------
#define CSTR 17

static __device__ inline void attn_step(short8v kc_, short8v qf, short8v v0c, short8v v1c,
                                        f32x16& o, float& rsA, float& rsB,
                                        const f32x16& zc, int hi) {
    f32x16 s = __builtin_amdgcn_mfma_f32_32x32x16_bf16(kc_, qf, zc, 0, 0, 0);
    // half 1: acc regs 0..7 (k rows 0..15) -> PV with v0
    {
        float e0 = fexp2(s[0]), e1 = fexp2(s[1]), e2 = fexp2(s[2]), e3 = fexp2(s[3]);
        float e4 = fexp2(s[4]), e5 = fexp2(s[5]), e6 = fexp2(s[6]), e7 = fexp2(s[7]);
        rsA += ((e0 + e1) + (e2 + e3)) + ((e4 + e5) + (e6 + e7));
        uint a0 = cvtpk(e0, e1), a1 = cvtpk(e2, e3);
        uint b0 = cvtpk(e4, e5), b1 = cvtpk(e6, e7);
        B8u B1;
        lswap(a0, b0, B1.u[0], B1.u[2], hi);
        lswap(a1, b1, B1.u[1], B1.u[3], hi);
        o = __builtin_amdgcn_mfma_f32_32x32x16_bf16(v0c, B1.v, o, 0, 0, 0);
    }
    // half 2: acc regs 8..15 (k rows 16..31) -> PV with v1
    {
        float e0 = fexp2(s[8]),  e1 = fexp2(s[9]),  e2 = fexp2(s[10]), e3 = fexp2(s[11]);
        float e4 = fexp2(s[12]), e5 = fexp2(s[13]), e6 = fexp2(s[14]), e7 = fexp2(s[15]);
        rsB += ((e0 + e1) + (e2 + e3)) + ((e4 + e5) + (e6 + e7));
        uint a0 = cvtpk(e0, e1), a1 = cvtpk(e2, e3);
        uint b0 = cvtpk(e4, e5), b1 = cvtpk(e6, e7);
        B8u B2;
        lswap(a0, b0, B2.u[0], B2.u[2], hi);
        lswap(a1, b1, B2.u[1], B2.u[3], hi);
        o = __builtin_amdgcn_mfma_f32_32x32x16_bf16(v1c, B2.v, o, 0, 0, 0);
    }
}

__global__ __launch_bounds__(256) void attn_kernel(const ushort* __restrict__ qpack,
                                                   const ushort* __restrict__ kpack,
                                                   const ushort* __restrict__ vpack,
                                                   const float* __restrict__ x,
                                                   float* __restrict__ out) {
    __shared__ float part[4][64][CSTR];    // 17.4 KB
    const int h = blockIdx.y, qc = blockIdx.x;
    const int tid = threadIdx.x, lane = tid & 63;
    const int kh = tid >> 6;               // key quarter 0..3
    const int q31 = lane & 31, hi = lane >> 5;

    short8v qf = *(const short8v*)&qpack[((size_t)(h * NQC + qc) * 64 + lane) * 8];

    const char* kp = (const char*)(kpack + ((size_t)(h * NKC + kh * KQRT) * 64 + lane) * 8);
    const char* vp = (const char*)(vpack + ((size_t)(h * NKC + kh * KQRT) * 2 * 64 + lane) * 8);

    short8v kf  = *(const short8v*)kp;
    short8v v0f = *(const short8v*)vp;
    short8v v1f = *(const short8v*)(vp + 1024);

    f32x16 o, zc;
    #pragma unroll
    for (int r = 0; r < 16; ++r) { o[r] = 0.0f; zc[r] = 0.0f; }
    float rsA = 0.0f, rsB = 0.0f;

    #pragma unroll 2
    for (int c = 0; c < KQRT - 1; ++c) {
        kp += 1024; vp += 2048;
        short8v kn  = *(const short8v*)kp;
        short8v v0n = *(const short8v*)vp;
        short8v v1n = *(const short8v*)(vp + 1024);
        attn_step(kf, qf, v0f, v1f, o, rsA, rsB, zc, hi);
        kf = kn; v0f = v0n; v1f = v1n;
    }
    attn_step(kf, qf, v0f, v1f, o, rsA, rsB, zc, hi);   // peeled last chunk

    float rs = rsA + rsB;
    rs += __shfl_xor(rs, 32);

    {
        float* pw = &part[kh][lane][0];
        #pragma unroll
        for (int r = 0; r < 16; ++r) pw[r] = o[r];
        pw[16] = rs;
    }
    __syncthreads();

    float rsAll = part[0][lane][16] + part[1][lane][16]
                + part[2][lane][16] + part[3][lane][16];
    float inv = 1.0f / rsAll;
    int q = qc * 32 + q31;
    #pragma unroll
    for (int i = 0; i < 4; ++i) {
        int r = 4 * kh + i;
        float val = part[0][lane][r] + part[1][lane][r]
                  + part[2][lane][r] + part[3][lane][r];
        int dv = i + 8 * kh + 4 * hi;
        size_t i0 = (size_t)(h * DV + dv) * NQ + q;
        out[i0] = val * inv + x[i0];
    }
}

// ---------------- launcher ----------------
extern "C" void kernel_launch(void* const* d_in, const int* in_sizes, int n_in,
                              void* d_out, int out_size, void* d_ws, size_t ws_size,
                              hipStream_t stream) {
    const float* x  = (const float*)d_in[0];
    const float* wq = (const float*)d_in[1];
    const float* bq = (const float*)d_in[2];
    const float* wk = (const float*)d_in[3];
    const float* bk = (const float*)d_in[4];
    const float* wv = (const float*)d_in[5];
    float* out = (float*)d_out;

    ushort* p = (ushort*)d_ws;
    ushort* qpack = p;  p += (size_t)NH * NQC * 64 * 8;      // 2.36 MB
    ushort* kpack = p;  p += (size_t)NH * NKC * 64 * 8;      // 0.59 MB
    ushort* vpack = p;  p += (size_t)NH * NKC * 2 * 64 * 8;  // 1.18 MB

    gemm_all<<<G_ALL, 256, 0, stream>>>(x, wq, bq, wk, bk, wv, qpack, kpack, vpack);
    attn_kernel<<<dim3(NQC, NH), 256, 0, stream>>>(qpack, kpack, vpack, x, out);
}